// Round 2
// baseline (181.749 us; speedup 1.0000x reference)
//
#include <hip/hip_runtime.h>
#include <hip/hip_bf16.h>
#include <stdint.h>

#define MARGIN   0.5f
#define POS_THR  (1.0f - 1e-5f)

typedef __attribute__((ext_vector_type(8))) short  short8;
typedef __attribute__((ext_vector_type(4))) float  f32x4;

#define BM 128
#define BN 128
#define BK 32

// ---------- helpers ----------
__device__ __forceinline__ ushort f2bf_rne(float x) {
  uint32_t u = __float_as_uint(x);
  u += 0x7fffu + ((u >> 16) & 1u);
  return (ushort)(u >> 16);
}

__device__ __forceinline__ void async_load16(const ushort* g, ushort* l) {
  // width-16 global->LDS DMA; LDS dest is wave-uniform base + lane*16B
  __builtin_amdgcn_global_load_lds(
      (__attribute__((address_space(1))) void*)(const_cast<ushort*>(g)),
      (__attribute__((address_space(3))) void*)(l),
      16, 0, 0);
}

// ---------- prep kernels ----------
__global__ void convert_bf16_kernel(const float* __restrict__ src,
                                    ushort* __restrict__ dst, int total4) {
  int i = blockIdx.x * blockDim.x + threadIdx.x;
  if (i >= total4) return;
  float4 v = reinterpret_cast<const float4*>(src)[i];
  ushort4 o;
  o.x = f2bf_rne(v.x); o.y = f2bf_rne(v.y);
  o.z = f2bf_rne(v.z); o.w = f2bf_rne(v.w);
  reinterpret_cast<ushort4*>(dst)[i] = o;
}

__global__ void zero_kernel(float* __restrict__ pos, float* __restrict__ neg,
                            int* __restrict__ cnt, int n) {
  int i = blockIdx.x * blockDim.x + threadIdx.x;
  if (i < n) { pos[i] = 0.f; neg[i] = 0.f; cnt[i] = 0; }
}

__global__ void count_kernel(const int* __restrict__ new_idx, int* __restrict__ cnt,
                             int n_new) {
  int i = blockIdx.x * blockDim.x + threadIdx.x;
  if (i < n_new) atomicAdd(&cnt[new_idx[i]], 1);
}

// ---------- main fused GEMM + masked-reduction kernel ----------
// sim = F*F^T (bf16 MFMA, fp32 accum). Per element (r,c):
//   r <  n_new: pos += cnt[c]*(1-s) if same&&s<POS_THR ; neg += s if diff&&s>MARGIN
//   r >= n_new: neg += cnt[c]*s     if diff&&s>MARGIN
__global__ __launch_bounds__(256) void simloss_kernel(
    const ushort* __restrict__ fb, const int* __restrict__ target,
    const int* __restrict__ cnt, float* __restrict__ pos_acc,
    float* __restrict__ neg_acc, int d, int n_new) {
  __shared__ __align__(16) ushort Als[BM * BK];
  __shared__ __align__(16) ushort Bls[BN * BK];
  __shared__ int   t_row[BM];
  __shared__ int   t_col[BN];
  __shared__ float cw_col[BN];
  __shared__ int   anycnt;

  const int tid = threadIdx.x;
  const int rowBase = blockIdx.y * BM;
  const int colBase = blockIdx.x * BN;

  // ---- block-skip test first: old-row blocks over no-new-col panels do nothing
  if (tid == 0) anycnt = 0;
  __syncthreads();
  if (tid < BN) {
    if (cnt[colBase + tid]) atomicOr(&anycnt, 1);
  }
  __syncthreads();
  if (rowBase >= n_new && anycnt == 0) return;

  if (tid < BM) t_row[tid] = target[rowBase + tid];
  if (tid < BN) {
    t_col[tid]  = target[colBase + tid];
    cw_col[tid] = (float)cnt[colBase + tid];
  }
  __syncthreads();

  const int lane = tid & 63;
  const int wid  = tid >> 6;        // 4 waves, 2x2 grid of 64x64 wave tiles
  const int wr   = wid >> 1;
  const int wc   = wid & 1;
  const int l15  = lane & 15;
  const int kb   = lane >> 4;       // k-octet selector 0..3

  f32x4 acc[4][4] = {};

  for (int k0 = 0; k0 < d; k0 += BK) {
    // stage A (rows) and B (cols) 128x32 bf16 tiles: 512 chunks of 16B each,
    // wave w issues chunks [(2w+cc)*64 + lane]; LDS stays linear (rule #21)
#pragma unroll
    for (int cc = 0; cc < 2; ++cc) {
      int ch = (wid * 2 + cc) * 64 + lane;
      int r  = ch >> 2;
      int kq = ch & 3;
      const ushort* gA = fb + (size_t)(rowBase + r) * d + (k0 + kq * 8);
      const ushort* gB = fb + (size_t)(colBase + r) * d + (k0 + kq * 8);
      async_load16(gA, &Als[(wid * 2 + cc) * 512]);
      async_load16(gB, &Bls[(wid * 2 + cc) * 512]);
    }
    __syncthreads();   // compiler drains vmcnt(0) before s_barrier

    short8 afr[4], bfr[4];
#pragma unroll
    for (int m = 0; m < 4; ++m)
      afr[m] = *reinterpret_cast<const short8*>(&Als[(wr * 64 + m * 16 + l15) * BK + kb * 8]);
#pragma unroll
    for (int nf = 0; nf < 4; ++nf)
      bfr[nf] = *reinterpret_cast<const short8*>(&Bls[(wc * 64 + nf * 16 + l15) * BK + kb * 8]);

#pragma unroll
    for (int m = 0; m < 4; ++m)
#pragma unroll
      for (int nf = 0; nf < 4; ++nf)
        acc[m][nf] = __builtin_amdgcn_mfma_f32_16x16x32_bf16(afr[m], bfr[nf], acc[m][nf], 0, 0, 0);
    __syncthreads();
  }

  // ---- epilogue: masked per-row reduction ----
  float cw[4]; int tc[4];
#pragma unroll
  for (int nf = 0; nf < 4; ++nf) {
    int cl = wc * 64 + nf * 16 + l15;
    cw[nf] = cw_col[cl];
    tc[nf] = t_col[cl];
  }

#pragma unroll
  for (int m = 0; m < 4; ++m) {
#pragma unroll
    for (int q = 0; q < 4; ++q) {
      int rl = wr * 64 + m * 16 + kb * 4 + q;     // C/D: row=(lane>>4)*4+reg, col=lane&15
      int r  = rowBase + rl;
      int tr = t_row[rl];
      bool isnew = (r < n_new);
      float p = 0.f, ng = 0.f;
#pragma unroll
      for (int nf = 0; nf < 4; ++nf) {
        float s = acc[m][nf][q];
        bool same = (tr == tc[nf]);
        if (isnew) {
          if (same && s < POS_THR)   p  += cw[nf] * (1.0f - s);
          if (!same && s > MARGIN)   ng += s;
        } else {
          if (!same && s > MARGIN)   ng += cw[nf] * s;
        }
      }
      // reduce across the 16 lanes (same kb group) sharing this output row
#pragma unroll
      for (int off = 8; off; off >>= 1) {
        p  += __shfl_xor(p, off);
        ng += __shfl_xor(ng, off);
      }
      if (l15 == 0) {
        if (p  != 0.f) atomicAdd(&pos_acc[r], p);
        if (ng != 0.f) atomicAdd(&neg_acc[r], ng);
      }
    }
  }
}

// ---------- finalize ----------
__global__ void finalize_kernel(const float* __restrict__ pos_acc,
                                const float* __restrict__ neg_acc,
                                float* __restrict__ out, int n, int n_new,
                                float alpha) {
  float beta = 1.0f - alpha;
  float local = 0.f;
  for (int i = threadIdx.x; i < n; i += blockDim.x) {
    if (i < n_new) local += alpha * pos_acc[i] + beta * neg_acc[i];
    else           local += beta * neg_acc[i];
  }
  if (threadIdx.x == 0 && n > n_new && n_new > 0)
    local += (float)(n - n_new) * alpha * pos_acc[n_new - 1];  // stale pos broadcast
#pragma unroll
  for (int off = 32; off; off >>= 1) local += __shfl_xor(local, off);
  __shared__ float red[4];
  int w = threadIdx.x >> 6, ln = threadIdx.x & 63;
  if (ln == 0) red[w] = local;
  __syncthreads();
  if (threadIdx.x == 0) out[0] = (red[0] + red[1] + red[2] + red[3]) / (float)n;
}

// ---------- launch ----------
extern "C" void kernel_launch(void* const* d_in, const int* in_sizes, int n_in,
                              void* d_out, int out_size, void* d_ws, size_t ws_size,
                              hipStream_t stream) {
  const float* feature = (const float*)d_in[0];
  const int*   target  = (const int*)d_in[1];
  const int*   new_idx = (const int*)d_in[2];

  const int n     = in_sizes[1];
  const int d     = in_sizes[0] / n;
  const int n_new = in_sizes[2];
  const int n_old = (n_in > 3) ? in_sizes[3] : 0;
  const float alpha = (n_old != 0) ? 0.9f : 0.5f;

  auto al = [](size_t x) { return (x + 255) & ~(size_t)255; };
  char* ws = (char*)d_ws;
  ushort* fb      = (ushort*)ws;
  size_t  off     = al((size_t)n * d * sizeof(ushort));
  float*  pos_acc = (float*)(ws + off); off += al((size_t)n * sizeof(float));
  float*  neg_acc = (float*)(ws + off); off += al((size_t)n * sizeof(float));
  int*    cnt     = (int*)(ws + off);

  int total4 = (n * d) / 4;
  convert_bf16_kernel<<<(total4 + 255) / 256, 256, 0, stream>>>(feature, fb, total4);
  zero_kernel<<<(n + 255) / 256, 256, 0, stream>>>(pos_acc, neg_acc, cnt, n);
  count_kernel<<<(n_new + 255) / 256, 256, 0, stream>>>(new_idx, cnt, n_new);

  dim3 grid(n / BN, n / BM);
  simloss_kernel<<<grid, 256, 0, stream>>>(fb, target, cnt, pos_acc, neg_acc, d, n_new);

  finalize_kernel<<<1, 256, 0, stream>>>(pos_acc, neg_acc, (float*)d_out, n, n_new, alpha);
}

// Round 3
// 144.532 us; speedup vs baseline: 1.2575x; 1.2575x over previous
//
#include <hip/hip_runtime.h>
#include <hip/hip_bf16.h>
#include <stdint.h>

#define MARGIN   0.5f
#define POS_THR  (1.0f - 1e-5f)

typedef __attribute__((ext_vector_type(8))) short  short8;
typedef __attribute__((ext_vector_type(4))) float  f32x4;

#define BM 128
#define BN 128
#define BK 32
#define NPANEL_SHIFT 7   // BN = 128

// ---------- helpers ----------
__device__ __forceinline__ ushort f2bf_rne(float x) {
  uint32_t u = __float_as_uint(x);
  u += 0x7fffu + ((u >> 16) & 1u);
  return (ushort)(u >> 16);
}

__device__ __forceinline__ void async_load16(const ushort* g, ushort* l) {
  // width-16 global->LDS DMA; LDS dest = wave-uniform base + lane*16B
  __builtin_amdgcn_global_load_lds(
      (__attribute__((address_space(1))) void*)(const_cast<ushort*>(g)),
      (__attribute__((address_space(3))) void*)(l),
      16, 0, 0);
}

// ---------- prep: f32->bf16 convert + zero accumulators/cnt/flags ----------
__global__ void prep_kernel(const float* __restrict__ src, ushort* __restrict__ dst,
                            float* __restrict__ pos, float* __restrict__ neg,
                            int* __restrict__ cnt, int* __restrict__ flags,
                            int total4, int n, int npanel) {
  int i = blockIdx.x * blockDim.x + threadIdx.x;
  if (i < total4) {
    float4 v = reinterpret_cast<const float4*>(src)[i];
    ushort4 o;
    o.x = f2bf_rne(v.x); o.y = f2bf_rne(v.y);
    o.z = f2bf_rne(v.z); o.w = f2bf_rne(v.w);
    reinterpret_cast<ushort4*>(dst)[i] = o;
  }
  if (i < n) { pos[i] = 0.f; neg[i] = 0.f; cnt[i] = 0; }
  if (i < npanel) flags[i] = 0;
}

// ---------- count: histogram new_idx + per-col-panel has-new flags ----------
__global__ void count_kernel(const int* __restrict__ new_idx, int* __restrict__ cnt,
                             int* __restrict__ flags, int n_new) {
  int i = blockIdx.x * blockDim.x + threadIdx.x;
  if (i < n_new) {
    int idx = new_idx[i];
    atomicAdd(&cnt[idx], 1);
    atomicOr(&flags[idx >> NPANEL_SHIFT], 1);
  }
}

// ---------- main fused GEMM + masked-reduction ----------
// sim = F*F^T (bf16 MFMA 16x16x32, fp32 accum), 128x128 tile, 4 waves (2x2 of
// 64x64), BK=32 double-buffered 2-phase, swizzled LDS (slot ^= (row>>1)&3,
// applied on the pre-swizzled GLOBAL source + on the ds_read — rule #21).
// Operands SWAPPED in the MFMA (mfma(B,A)) so each lane's outputs per m all
// share one sim-row -> row reduction is lane-local + 2 shfl.
__global__ __launch_bounds__(256) void simloss_kernel(
    const ushort* __restrict__ fb, const int* __restrict__ target,
    const int* __restrict__ cnt, const int* __restrict__ colHasNew,
    float* __restrict__ pos_acc, float* __restrict__ neg_acc,
    int d, int n_new) {
  __shared__ __align__(16) ushort Als[2][BM * BK];
  __shared__ __align__(16) ushort Bls[2][BN * BK];
  __shared__ int   t_row[BM];
  __shared__ int   t_col[BN];
  __shared__ float cw_col[BN];

  const int tid = threadIdx.x;
  const int rowBase = blockIdx.y * BM;
  const int colBase = blockIdx.x * BN;

  // old-row block over a panel with no new cols: contributes nothing
  if (rowBase >= n_new && colHasNew[blockIdx.x] == 0) return;

  if (tid < BM) t_row[tid] = target[rowBase + tid];
  if (tid < BN) {
    t_col[tid]  = target[colBase + tid];
    cw_col[tid] = (float)cnt[colBase + tid];
  }

  const int lane = tid & 63;
  const int wid  = tid >> 6;        // 4 waves, 2x2 grid of 64x64 wave tiles
  const int wr   = wid >> 1;
  const int wc   = wid & 1;
  const int l15  = lane & 15;
  const int kb   = lane >> 4;       // k-octet selector 0..3

  // ---- staging: 512 16B-chunks per 128x32 tile; wave w issues chunks
  // (2w+cc)*64+lane. Global source carries the involution slot^=(row>>1)&3
  // so linear gload_lds dest + swizzled ds_read line up.
  const int ch0 = (wid * 2 + 0) * 64 + lane;
  const int ch1 = (wid * 2 + 1) * 64 + lane;
  const int r0 = ch0 >> 2, kq0 = (ch0 & 3) ^ ((ch0 >> 3) & 3);
  const int r1 = ch1 >> 2, kq1 = (ch1 & 3) ^ ((ch1 >> 3) & 3);
  const ushort* gA0 = fb + (size_t)(rowBase + r0) * d + kq0 * 8;
  const ushort* gA1 = fb + (size_t)(rowBase + r1) * d + kq1 * 8;
  const ushort* gB0 = fb + (size_t)(colBase + r0) * d + kq0 * 8;
  const ushort* gB1 = fb + (size_t)(colBase + r1) * d + kq1 * 8;
  const int lo0 = (wid * 2 + 0) * 512;   // ushort offset of wave's chunk run
  const int lo1 = (wid * 2 + 1) * 512;

  f32x4 acc[4][4] = {};

  // swizzled ds_read offsets (ushort units): row*32 + (kb ^ ((row>>1)&3))*8
  int aoff[4], boff[4];
#pragma unroll
  for (int m = 0; m < 4; ++m) {
    int row = wr * 64 + m * 16 + l15;
    aoff[m] = row * 32 + ((kb ^ ((row >> 1) & 3)) * 8);
  }
#pragma unroll
  for (int nf = 0; nf < 4; ++nf) {
    int row = wc * 64 + nf * 16 + l15;
    boff[nf] = row * 32 + ((kb ^ ((row >> 1) & 3)) * 8);
  }

  // prologue: stage k=0 into buf0
  async_load16(gA0, &Als[0][lo0]);
  async_load16(gA1, &Als[0][lo1]);
  async_load16(gB0, &Bls[0][lo0]);
  async_load16(gB1, &Bls[0][lo1]);
  __syncthreads();

  const int nk = d / BK;
  for (int t = 0; t < nk; ++t) {
    const int b = t & 1;
    if (t + 1 < nk) {          // stage next tile into the other buffer
      int ko = (t + 1) * BK;
      async_load16(gA0 + ko, &Als[b ^ 1][lo0]);
      async_load16(gA1 + ko, &Als[b ^ 1][lo1]);
      async_load16(gB0 + ko, &Bls[b ^ 1][lo0]);
      async_load16(gB1 + ko, &Bls[b ^ 1][lo1]);
    }
    short8 afr[4], bfr[4];
#pragma unroll
    for (int m = 0; m < 4; ++m)
      afr[m] = *reinterpret_cast<const short8*>(&Als[b][aoff[m]]);
#pragma unroll
    for (int nf = 0; nf < 4; ++nf)
      bfr[nf] = *reinterpret_cast<const short8*>(&Bls[b][boff[nf]]);

    // swapped operands: acc[m][nf] holds sim^T fragment ->
    // row = rowBase + wr*64+m*16+l15 (lane-fixed!), col = colBase+wc*64+nf*16+kb*4+q
#pragma unroll
    for (int m = 0; m < 4; ++m)
#pragma unroll
      for (int nf = 0; nf < 4; ++nf)
        acc[m][nf] = __builtin_amdgcn_mfma_f32_16x16x32_bf16(bfr[nf], afr[m], acc[m][nf], 0, 0, 0);
    __syncthreads();           // one barrier per kstep: drains stage + frag reads
  }

  // ---- epilogue: per-row masked reduction, mostly lane-local ----
  int tc_r[4][4]; float cw_r[4][4];
#pragma unroll
  for (int nf = 0; nf < 4; ++nf)
#pragma unroll
    for (int q = 0; q < 4; ++q) {
      int cl = wc * 64 + nf * 16 + kb * 4 + q;
      tc_r[nf][q] = t_col[cl];
      cw_r[nf][q] = cw_col[cl];
    }

#pragma unroll
  for (int m = 0; m < 4; ++m) {
    int rl = wr * 64 + m * 16 + l15;
    int r  = rowBase + rl;
    int tr = t_row[rl];
    bool isnew = (r < n_new);
    float p = 0.f, ng = 0.f;
#pragma unroll
    for (int nf = 0; nf < 4; ++nf)
#pragma unroll
      for (int q = 0; q < 4; ++q) {
        float s = acc[m][nf][q];
        bool same = (tr == tc_r[nf][q]);
        if (isnew) {
          if (same && s < POS_THR)  p  += cw_r[nf][q] * (1.0f - s);
          if (!same && s > MARGIN)  ng += s;
        } else {
          if (!same && s > MARGIN)  ng += cw_r[nf][q] * s;
        }
      }
    // rows are replicated across the 4 kb groups -> 2-step butterfly
    p  += __shfl_xor(p, 16);  p  += __shfl_xor(p, 32);
    ng += __shfl_xor(ng, 16); ng += __shfl_xor(ng, 32);
    if (lane < 16) {
      if (p  != 0.f) atomicAdd(&pos_acc[r], p);
      if (ng != 0.f) atomicAdd(&neg_acc[r], ng);
    }
  }
}

// ---------- finalize ----------
__global__ void finalize_kernel(const float* __restrict__ pos_acc,
                                const float* __restrict__ neg_acc,
                                float* __restrict__ out, int n, int n_new,
                                float alpha) {
  float beta = 1.0f - alpha;
  float local = 0.f;
  int n4 = n >> 2;
  for (int i = threadIdx.x; i < n4; i += blockDim.x) {
    float4 pv = reinterpret_cast<const float4*>(pos_acc)[i];
    float4 nv = reinterpret_cast<const float4*>(neg_acc)[i];
    int r = i * 4;
    local += (r + 0 < n_new) ? alpha * pv.x + beta * nv.x : beta * nv.x;
    local += (r + 1 < n_new) ? alpha * pv.y + beta * nv.y : beta * nv.y;
    local += (r + 2 < n_new) ? alpha * pv.z + beta * nv.z : beta * nv.z;
    local += (r + 3 < n_new) ? alpha * pv.w + beta * nv.w : beta * nv.w;
  }
  if (threadIdx.x == 0 && n > n_new && n_new > 0)
    local += (float)(n - n_new) * alpha * pos_acc[n_new - 1];  // stale pos broadcast
#pragma unroll
  for (int off = 32; off; off >>= 1) local += __shfl_xor(local, off);
  __shared__ float red[4];
  int w = threadIdx.x >> 6, ln = threadIdx.x & 63;
  if (ln == 0) red[w] = local;
  __syncthreads();
  if (threadIdx.x == 0) out[0] = (red[0] + red[1] + red[2] + red[3]) / (float)n;
}

// ---------- launch ----------
extern "C" void kernel_launch(void* const* d_in, const int* in_sizes, int n_in,
                              void* d_out, int out_size, void* d_ws, size_t ws_size,
                              hipStream_t stream) {
  const float* feature = (const float*)d_in[0];
  const int*   target  = (const int*)d_in[1];
  const int*   new_idx = (const int*)d_in[2];

  const int n     = in_sizes[1];
  const int d     = in_sizes[0] / n;
  const int n_new = in_sizes[2];
  const int n_old = (n_in > 3) ? in_sizes[3] : 0;
  const float alpha = (n_old != 0) ? 0.9f : 0.5f;
  const int npanel = n / BN;

  auto al = [](size_t x) { return (x + 255) & ~(size_t)255; };
  char* ws = (char*)d_ws;
  ushort* fb      = (ushort*)ws;
  size_t  off     = al((size_t)n * d * sizeof(ushort));
  float*  pos_acc = (float*)(ws + off); off += al((size_t)n * sizeof(float));
  float*  neg_acc = (float*)(ws + off); off += al((size_t)n * sizeof(float));
  int*    cnt     = (int*)(ws + off);   off += al((size_t)n * sizeof(int));
  int*    flags   = (int*)(ws + off);

  int total4 = (n * d) / 4;
  prep_kernel<<<(total4 + 255) / 256, 256, 0, stream>>>(feature, fb, pos_acc,
                                                        neg_acc, cnt, flags,
                                                        total4, n, npanel);
  count_kernel<<<(n_new + 255) / 256, 256, 0, stream>>>(new_idx, cnt, flags, n_new);

  dim3 grid(n / BN, n / BM);
  simloss_kernel<<<grid, 256, 0, stream>>>(fb, target, cnt, flags,
                                           pos_acc, neg_acc, d, n_new);

  finalize_kernel<<<1, 256, 0, stream>>>(pos_acc, neg_acc, (float*)d_out, n, n_new, alpha);
}

// Round 4
// 142.011 us; speedup vs baseline: 1.2798x; 1.0178x over previous
//
#include <hip/hip_runtime.h>
#include <hip/hip_bf16.h>
#include <stdint.h>

#define MARGIN   0.5f
#define POS_THR  (1.0f - 1e-5f)

typedef __attribute__((ext_vector_type(8))) short  short8;
typedef __attribute__((ext_vector_type(4))) float  f32x4;

#define BM 128
#define BN 128
#define BK 32
#define NPANEL_SHIFT 7   // BN = 128

// ---------- helpers ----------
__device__ __forceinline__ ushort f2bf_rne(float x) {
  uint32_t u = __float_as_uint(x);
  u += 0x7fffu + ((u >> 16) & 1u);
  return (ushort)(u >> 16);
}

__device__ __forceinline__ void async_load16(const ushort* g, ushort* l) {
  // width-16 global->LDS DMA; LDS dest = wave-uniform base + lane*16B
  __builtin_amdgcn_global_load_lds(
      (__attribute__((address_space(1))) void*)(const_cast<ushort*>(g)),
      (__attribute__((address_space(3))) void*)(l),
      16, 0, 0);
}

// ---------- prep: f32->bf16 convert + zero accumulators/cnt/flags ----------
__global__ void prep_kernel(const float* __restrict__ src, ushort* __restrict__ dst,
                            float* __restrict__ pos, float* __restrict__ neg,
                            int* __restrict__ cnt, int* __restrict__ flags,
                            int total4, int n, int npanel) {
  int i = blockIdx.x * blockDim.x + threadIdx.x;
  if (i < total4) {
    float4 v = reinterpret_cast<const float4*>(src)[i];
    ushort4 o;
    o.x = f2bf_rne(v.x); o.y = f2bf_rne(v.y);
    o.z = f2bf_rne(v.z); o.w = f2bf_rne(v.w);
    reinterpret_cast<ushort4*>(dst)[i] = o;
  }
  if (i < n) { pos[i] = 0.f; neg[i] = 0.f; cnt[i] = 0; }
  if (i < npanel) flags[i] = 0;
}

// ---------- count: histogram new_idx + per-col-panel has-new flags ----------
__global__ void count_kernel(const int* __restrict__ new_idx, int* __restrict__ cnt,
                             int* __restrict__ flags, int n_new) {
  int i = blockIdx.x * blockDim.x + threadIdx.x;
  if (i < n_new) {
    int idx = new_idx[i];
    atomicAdd(&cnt[idx], 1);
    atomicOr(&flags[idx >> NPANEL_SHIFT], 1);
  }
}

// ---------- main fused GEMM + masked-reduction ----------
// sim = F*F^T (bf16 MFMA 16x16x32, fp32 accum), 128x128 tile, 4 waves (2x2),
// 3-buffer ring pipeline: counted vmcnt(4) + ONE raw s_barrier per kstep,
// loads for tile t+1 stay in flight across the barrier (T3/T4-minimum).
// LDS swizzle slot^=(row>>1)&3 on pre-swizzled GLOBAL src + ds_read (rule #21).
// MFMA operands swapped so each lane's outputs share one sim-row.
__global__ __launch_bounds__(256) void simloss_kernel(
    const ushort* __restrict__ fb, const int* __restrict__ target,
    const int* __restrict__ cnt, const int* __restrict__ colHasNew,
    float* __restrict__ pos_acc, float* __restrict__ neg_acc,
    int d, int n_new) {
  __shared__ __align__(16) ushort Als[3][BM * BK];
  __shared__ __align__(16) ushort Bls[3][BN * BK];
  __shared__ int   t_row[BM];
  __shared__ int   t_col[BN];
  __shared__ float cw_col[BN];

  const int tid = threadIdx.x;
  const int rowBase = blockIdx.y * BM;
  const int colBase = blockIdx.x * BN;

  // old-row block over a panel with no new cols: contributes nothing
  if (rowBase >= n_new && colHasNew[blockIdx.x] == 0) return;

  if (tid < BM) t_row[tid] = target[rowBase + tid];
  if (tid < BN) {
    t_col[tid]  = target[colBase + tid];
    cw_col[tid] = (float)cnt[colBase + tid];
  }

  const int lane = tid & 63;
  const int wid  = tid >> 6;        // 4 waves, 2x2 grid of 64x64 wave tiles
  const int wr   = wid >> 1;
  const int wc   = wid & 1;
  const int l15  = lane & 15;
  const int kb   = lane >> 4;       // k-octet selector 0..3

  // staging geometry: 512 16B-chunks per 128x32 tile; wave w issues chunks
  // (2w+cc)*64+lane; global source pre-swizzled with involution slot^=(row>>1)&3
  const int ch0 = (wid * 2 + 0) * 64 + lane;
  const int ch1 = (wid * 2 + 1) * 64 + lane;
  const int r0 = ch0 >> 2, kq0 = (ch0 & 3) ^ ((ch0 >> 3) & 3);
  const int r1 = ch1 >> 2, kq1 = (ch1 & 3) ^ ((ch1 >> 3) & 3);
  const ushort* gA0 = fb + (size_t)(rowBase + r0) * d + kq0 * 8;
  const ushort* gA1 = fb + (size_t)(rowBase + r1) * d + kq1 * 8;
  const ushort* gB0 = fb + (size_t)(colBase + r0) * d + kq0 * 8;
  const ushort* gB1 = fb + (size_t)(colBase + r1) * d + kq1 * 8;
  const int lo0 = (wid * 2 + 0) * 512;
  const int lo1 = (wid * 2 + 1) * 512;

  f32x4 acc[4][4] = {};

  // swizzled ds_read offsets (ushort units): row*32 + (kb ^ ((row>>1)&3))*8
  int aoff[4], boff[4];
#pragma unroll
  for (int m = 0; m < 4; ++m) {
    int row = wr * 64 + m * 16 + l15;
    aoff[m] = row * 32 + ((kb ^ ((row >> 1) & 3)) * 8);
  }
#pragma unroll
  for (int nf = 0; nf < 4; ++nf) {
    int row = wc * 64 + nf * 16 + l15;
    boff[nf] = row * 32 + ((kb ^ ((row >> 1) & 3)) * 8);
  }

  // drain metadata loads so manual vmcnt counts are exact (in-order retire)
  asm volatile("s_waitcnt vmcnt(0) lgkmcnt(0)" ::: "memory");
  __builtin_amdgcn_sched_barrier(0);

  // prologue: stage tiles 0 and 1 (8 loads in flight)
  async_load16(gA0, &Als[0][lo0]);
  async_load16(gA1, &Als[0][lo1]);
  async_load16(gB0, &Bls[0][lo0]);
  async_load16(gB1, &Bls[0][lo1]);
  const int nk = d / BK;
  if (nk > 1) {
    async_load16(gA0 + BK, &Als[1][lo0]);
    async_load16(gA1 + BK, &Als[1][lo1]);
    async_load16(gB0 + BK, &Bls[1][lo0]);
    async_load16(gB1 + BK, &Bls[1][lo1]);
  }

  int cur = 0;
  for (int t = 0; t < nk; ++t) {
    // tile t landed when ≤4 (tile t+1's) loads remain outstanding
    if (t == nk - 1) asm volatile("s_waitcnt vmcnt(0)" ::: "memory");
    else             asm volatile("s_waitcnt vmcnt(4)" ::: "memory");
    __builtin_amdgcn_s_barrier();
    __builtin_amdgcn_sched_barrier(0);

    // issue tile t+2 into ring slot (cur+2)%3 — its last readers passed the barrier
    if (t + 2 < nk) {
      int nxt = cur + 2; if (nxt >= 3) nxt -= 3;
      int ko = (t + 2) * BK;
      async_load16(gA0 + ko, &Als[nxt][lo0]);
      async_load16(gA1 + ko, &Als[nxt][lo1]);
      async_load16(gB0 + ko, &Bls[nxt][lo0]);
      async_load16(gB1 + ko, &Bls[nxt][lo1]);
    }

    short8 afr[4], bfr[4];
#pragma unroll
    for (int m = 0; m < 4; ++m)
      afr[m] = *reinterpret_cast<const short8*>(&Als[cur][aoff[m]]);
#pragma unroll
    for (int nf = 0; nf < 4; ++nf)
      bfr[nf] = *reinterpret_cast<const short8*>(&Bls[cur][boff[nf]]);
    asm volatile("s_waitcnt lgkmcnt(0)" ::: "memory");
    __builtin_amdgcn_sched_barrier(0);          // rule #18: keep MFMA below

    // swapped operands: acc[m][nf] row = rowBase+wr*64+m*16+l15 (lane-fixed),
    // col = colBase+wc*64+nf*16+kb*4+q
#pragma unroll
    for (int m = 0; m < 4; ++m)
#pragma unroll
      for (int nf = 0; nf < 4; ++nf)
        acc[m][nf] = __builtin_amdgcn_mfma_f32_16x16x32_bf16(bfr[nf], afr[m], acc[m][nf], 0, 0, 0);

    cur = (cur + 1 == 3) ? 0 : cur + 1;
  }

  // ---- epilogue: per-row masked reduction, mostly lane-local ----
  int tc_r[4][4]; float cw_r[4][4];
#pragma unroll
  for (int nf = 0; nf < 4; ++nf)
#pragma unroll
    for (int q = 0; q < 4; ++q) {
      int cl = wc * 64 + nf * 16 + kb * 4 + q;
      tc_r[nf][q] = t_col[cl];
      cw_r[nf][q] = cw_col[cl];
    }

#pragma unroll
  for (int m = 0; m < 4; ++m) {
    int rl = wr * 64 + m * 16 + l15;
    int r  = rowBase + rl;
    int tr = t_row[rl];
    bool isnew = (r < n_new);
    float p = 0.f, ng = 0.f;
#pragma unroll
    for (int nf = 0; nf < 4; ++nf)
#pragma unroll
      for (int q = 0; q < 4; ++q) {
        float s = acc[m][nf][q];
        bool same = (tr == tc_r[nf][q]);
        if (isnew) {
          if (same && s < POS_THR)  p  += cw_r[nf][q] * (1.0f - s);
          if (!same && s > MARGIN)  ng += s;
        } else {
          if (!same && s > MARGIN)  ng += cw_r[nf][q] * s;
        }
      }
    // rows replicated across the 4 kb groups -> 2-step butterfly
    p  += __shfl_xor(p, 16);  p  += __shfl_xor(p, 32);
    ng += __shfl_xor(ng, 16); ng += __shfl_xor(ng, 32);
    if (lane < 16) {
      if (p  != 0.f) atomicAdd(&pos_acc[r], p);
      if (ng != 0.f) atomicAdd(&neg_acc[r], ng);
    }
  }
}

// ---------- finalize ----------
__global__ __launch_bounds__(1024) void finalize_kernel(
    const float* __restrict__ pos_acc, const float* __restrict__ neg_acc,
    float* __restrict__ out, int n, int n_new, float alpha) {
  float beta = 1.0f - alpha;
  float local = 0.f;
  int n4 = n >> 2;
  for (int i = threadIdx.x; i < n4; i += blockDim.x) {
    float4 pv = reinterpret_cast<const float4*>(pos_acc)[i];
    float4 nv = reinterpret_cast<const float4*>(neg_acc)[i];
    int r = i * 4;
    local += (r + 0 < n_new) ? alpha * pv.x + beta * nv.x : beta * nv.x;
    local += (r + 1 < n_new) ? alpha * pv.y + beta * nv.y : beta * nv.y;
    local += (r + 2 < n_new) ? alpha * pv.z + beta * nv.z : beta * nv.z;
    local += (r + 3 < n_new) ? alpha * pv.w + beta * nv.w : beta * nv.w;
  }
  if (threadIdx.x == 0 && n > n_new && n_new > 0)
    local += (float)(n - n_new) * alpha * pos_acc[n_new - 1];  // stale pos broadcast
#pragma unroll
  for (int off = 32; off; off >>= 1) local += __shfl_xor(local, off);
  __shared__ float red[16];
  int w = threadIdx.x >> 6, ln = threadIdx.x & 63;
  if (ln == 0) red[w] = local;
  __syncthreads();
  if (threadIdx.x == 0) {
    float s = 0.f;
    int nw = blockDim.x >> 6;
    for (int i = 0; i < nw; ++i) s += red[i];
    out[0] = s / (float)n;
  }
}

// ---------- launch ----------
extern "C" void kernel_launch(void* const* d_in, const int* in_sizes, int n_in,
                              void* d_out, int out_size, void* d_ws, size_t ws_size,
                              hipStream_t stream) {
  const float* feature = (const float*)d_in[0];
  const int*   target  = (const int*)d_in[1];
  const int*   new_idx = (const int*)d_in[2];

  const int n     = in_sizes[1];
  const int d     = in_sizes[0] / n;
  const int n_new = in_sizes[2];
  const int n_old = (n_in > 3) ? in_sizes[3] : 0;
  const float alpha = (n_old != 0) ? 0.9f : 0.5f;
  const int npanel = n / BN;

  auto al = [](size_t x) { return (x + 255) & ~(size_t)255; };
  char* ws = (char*)d_ws;
  ushort* fb      = (ushort*)ws;
  size_t  off     = al((size_t)n * d * sizeof(ushort));
  float*  pos_acc = (float*)(ws + off); off += al((size_t)n * sizeof(float));
  float*  neg_acc = (float*)(ws + off); off += al((size_t)n * sizeof(float));
  int*    cnt     = (int*)(ws + off);   off += al((size_t)n * sizeof(int));
  int*    flags   = (int*)(ws + off);

  int total4 = (n * d) / 4;
  prep_kernel<<<(total4 + 255) / 256, 256, 0, stream>>>(feature, fb, pos_acc,
                                                        neg_acc, cnt, flags,
                                                        total4, n, npanel);
  count_kernel<<<(n_new + 255) / 256, 256, 0, stream>>>(new_idx, cnt, flags, n_new);

  dim3 grid(n / BN, n / BM);
  simloss_kernel<<<grid, 256, 0, stream>>>(fb, target, cnt, flags,
                                           pos_acc, neg_acc, d, n_new);

  finalize_kernel<<<1, 1024, 0, stream>>>(pos_acc, neg_acc, (float*)d_out, n, n_new, alpha);
}